// Round 13
// baseline (212.056 us; speedup 1.0000x reference)
//
#include <hip/hip_runtime.h>

#define BATCH 8192
#define DIM   512
#define NTILE 1056          // 64 straddle + 992 above-diagonal 128x256 tiles

typedef __attribute__((ext_vector_type(4))) float  f32x4;
typedef __attribute__((ext_vector_type(8))) __bf16 bf16x8;

__device__ __forceinline__ unsigned short f2bf(float x) {
  unsigned u = __float_as_uint(x);
  u = (u + 0x7FFFu + ((u >> 16) & 1u)) >> 16;   // RNE
  return (unsigned short)u;
}

__device__ __forceinline__ void load_lds16(const void* g, void* l) {
  __builtin_amdgcn_global_load_lds(
      (__attribute__((address_space(1))) void*)(g),
      (__attribute__((address_space(3))) void*)(l), 16, 0, 0);
}

// monotone float <-> uint encoding (order-preserving); sentinels 0x00000000 / 0xFFFFFFFF
__device__ __forceinline__ unsigned enc(float f) {
  unsigned u = __float_as_uint(f);
  return u ^ (unsigned)(((int)u >> 31) | 0x80000000);
}
__device__ __forceinline__ float dec(unsigned k) {
  unsigned u = (k & 0x80000000u) ? (k ^ 0x80000000u) : ~k;
  return __uint_as_float(u);
}

// ---------------- prep: fp32->bf16, row norms, sentinel seeding, ctrl zeroing --------------
__global__ __launch_bounds__(256) void prep_kernel(
    const float* __restrict__ X, unsigned short* __restrict__ Xb,
    float* __restrict__ sq, unsigned* __restrict__ ctrl,
    uint4* __restrict__ pos4, uint4* __restrict__ neg4) {
  int gid = blockIdx.x * 256 + threadIdx.x;
  if (gid == 0) {
    ((float*)ctrl)[0] = 0.f;                   // sum of terms
    ((float*)ctrl)[1] = 0.f;                   // count
    ctrl[2] = 0u;                              // finish ticket
    ctrl[3] = 0u;                              // tile queue head
  }
  if (gid < 196608) {                          // 96 slots * 8192 * 4B / 16B
    pos4[gid] = (uint4){0u, 0u, 0u, 0u};       // enc-min sentinel (loses every max)
    neg4[gid] = (uint4){~0u, ~0u, ~0u, ~0u};   // enc-max sentinel (loses every min)
  }
  int wave = threadIdx.x >> 6, lane = threadIdx.x & 63;
  int row = blockIdx.x * 4 + wave;             // 2048 blocks * 4 waves = 8192 rows
  const float4* xr = (const float4*)(X + (size_t)row * DIM);
  float4 a = xr[lane * 2];
  float4 b = xr[lane * 2 + 1];
  float s = a.x*a.x + a.y*a.y + a.z*a.z + a.w*a.w
          + b.x*b.x + b.y*b.y + b.z*b.z + b.w*b.w;
  uint4 p;
  p.x = (unsigned)f2bf(a.x) | ((unsigned)f2bf(a.y) << 16);
  p.y = (unsigned)f2bf(a.z) | ((unsigned)f2bf(a.w) << 16);
  p.z = (unsigned)f2bf(b.x) | ((unsigned)f2bf(b.y) << 16);
  p.w = (unsigned)f2bf(b.z) | ((unsigned)f2bf(b.w) << 16);
  ((uint4*)(Xb + (size_t)row * DIM))[lane] = p;
  #pragma unroll
  for (int off = 32; off > 0; off >>= 1) s += __shfl_down(s, off);
  if (lane == 0) sq[row] = s;
}

// Epilogue for one 128x256 tile — z-trick: mine z = d^2 = (sq_j - 2a) + sq_i for BOTH
// directions (monotone per-row and per-column); masked operands zp/zn shared by the
// row and column reductions. 9 VALU/elem (was 11).
template<bool STRAD>
__device__ __forceinline__ void epilogue(
    const f32x4 (&acc)[4][8], const float* __restrict__ sq,
    const int* __restrict__ labels,
    int i0, int jwin, int wm, int wn, int quad, int lc,
    unsigned (*ibuf)[128][2], unsigned (*jbuf)[256][2]) {
  float sqj_r[8]; int labj_r[8];
  #pragma unroll
  for (int ni = 0; ni < 8; ni++) {
    int j = jwin + wn * 128 + ni * 16 + lc;
    sqj_r[ni] = sq[j]; labj_r[ni] = labels[j];
  }
  float rpos[16], rneg[16];
  float jp[8], jn[8];
  #pragma unroll
  for (int x = 0; x < 8; x++) { jp[x] = -3e38f; jn[x] = 3e38f; }
  #pragma unroll
  for (int mi = 0; mi < 4; mi++) {
    #pragma unroll
    for (int r = 0; r < 4; r++) {
      int ig = i0 + wm * 64 + mi * 16 + quad * 4 + r;
      int li = labels[ig];
      float si = sq[ig];
      float rp = -3e38f, rn = 3e38f;
      #pragma unroll
      for (int ni = 0; ni < 8; ni++) {
        float z = fmaf(-2.f, acc[mi][ni][r], sqj_r[ni]) + si;   // d^2
        bool same = (li == labj_r[ni]);
        bool posok = same;
        if (STRAD) posok = same && ((jwin + wn * 128 + ni * 16 + lc) != ig);
        float zp = posok ? z : -3e38f;
        float zn = same ? 3e38f : z;
        rp = fmaxf(rp, zp);
        rn = fminf(rn, zn);
        if (!STRAD) {                              // shared operands: col mining for free-ish
          jp[ni] = fmaxf(jp[ni], zp);
          jn[ni] = fminf(jn[ni], zn);
        }
      }
      rpos[mi * 4 + r] = rp; rneg[mi * 4 + r] = rn;
    }
  }
  #pragma unroll
  for (int m = 1; m <= 8; m <<= 1)
    #pragma unroll
    for (int x = 0; x < 16; x++) {
      rpos[x] = fmaxf(rpos[x], __shfl_xor(rpos[x], m));
      rneg[x] = fminf(rneg[x], __shfl_xor(rneg[x], m));
    }
  if (lc == 0) {
    #pragma unroll
    for (int mi = 0; mi < 4; mi++)
      #pragma unroll
      for (int r = 0; r < 4; r++) {
        int row = wm * 64 + mi * 16 + quad * 4 + r;
        ibuf[wn][row][0] = enc(rpos[mi * 4 + r]);
        ibuf[wn][row][1] = enc(rneg[mi * 4 + r]);
      }
  }
  if (!STRAD) {
    #pragma unroll
    for (int m = 16; m <= 32; m <<= 1)
      #pragma unroll
      for (int x = 0; x < 8; x++) {
        jp[x] = fmaxf(jp[x], __shfl_xor(jp[x], m));
        jn[x] = fminf(jn[x], __shfl_xor(jn[x], m));
      }
    if (quad == 0) {
      #pragma unroll
      for (int ni = 0; ni < 8; ni++) {
        int col = wn * 128 + ni * 16 + lc;
        jbuf[wm][col][0] = enc(jp[ni]);
        jbuf[wm][col][1] = enc(jn[ni]);
      }
    }
  }
}

// ---------------- main: R7/R12 config (best measured: 66us), z-trick epilogue --------------
// 1056 tiles of 128x256, dynamic atomic queue, 2 blocks/CU, XOR-swizzled LDS
// (0 conflicts), plain enc-uint stores to disjoint slots. NO fences, NO per-tile
// device sync (R3/R8/R11: any per-tile device-scope sync costs 2-4x).
__global__ __launch_bounds__(256, 2) void triplet_mfma(
    const unsigned short* __restrict__ Xb, const float* __restrict__ sq,
    const int* __restrict__ labels, unsigned* __restrict__ ctrl,
    unsigned* __restrict__ pos_i, unsigned* __restrict__ neg_i,
    unsigned* __restrict__ pos_j, unsigned* __restrict__ neg_j) {
  __shared__ __align__(16) unsigned short Asm[128 * 64];  // 16 KB
  __shared__ __align__(16) unsigned short Bsm[256 * 64];  // 32 KB
  __shared__ unsigned ibuf[2][128][2];                    // 2 KB
  __shared__ unsigned jbuf[2][256][2];                    // 4 KB
  __shared__ int tshare;

  int tid = threadIdx.x;
  int wave = tid >> 6, lane = tid & 63;
  int wm = wave >> 1, wn = wave & 1;
  int quad = lane >> 4, lc = lane & 15;
  int rc = lane >> 3;
  int gcol = ((lane & 7) ^ rc) * 8;          // XOR swizzle (verified: 0 conflicts)

  for (;;) {
    if (tid == 0) tshare = (int)atomicAdd(&ctrl[3], 1u);
    __syncthreads();
    int t = tshare;
    if (t >= NTILE) break;

    int It, Js; bool strad;
    if (t < 64) { It = t; Js = t >> 1; strad = true; }
    else {
      int u = t - 64; It = 0; Js = 0; strad = false;
      for (int s = 0; s < 64; s++) {
        int c = 31 - (s >> 1);
        if (u < c) { It = s; Js = (s >> 1) + 1 + u; break; }
        u -= c;
      }
    }
    int i0 = It * 128, jwin = Js * 256;

    f32x4 acc[4][8];
    #pragma unroll
    for (int mi = 0; mi < 4; mi++)
      #pragma unroll
      for (int ni = 0; ni < 8; ni++)
        acc[mi][ni] = (f32x4){0.f, 0.f, 0.f, 0.f};

    for (int k0 = 0; k0 < DIM; k0 += 64) {
      #pragma unroll
      for (int tt = 0; tt < 4; tt++) {
        int c = wave * 4 + tt;
        int row = c * 8 + rc;
        load_lds16(Xb + (size_t)(i0 + row) * DIM + k0 + gcol, &Asm[c * 512]);
      }
      #pragma unroll
      for (int tt = 0; tt < 8; tt++) {
        int c = wave * 8 + tt;
        int row = c * 8 + rc;
        load_lds16(Xb + (size_t)(jwin + row) * DIM + k0 + gcol, &Bsm[c * 512]);
      }
      __syncthreads();
      #pragma unroll
      for (int kk = 0; kk < 64; kk += 32) {
        int kc = kk >> 3;
        int asel = ((kc + quad) ^ (lc & 7)) * 8;
        bf16x8 af[4], bfr[8];
        #pragma unroll
        for (int mi = 0; mi < 4; mi++)
          af[mi] = *(const bf16x8*)&Asm[(wm * 64 + mi * 16 + lc) * 64 + asel];
        #pragma unroll
        for (int ni = 0; ni < 8; ni++)
          bfr[ni] = *(const bf16x8*)&Bsm[(wn * 128 + ni * 16 + lc) * 64 + asel];
        #pragma unroll
        for (int mi = 0; mi < 4; mi++)
          #pragma unroll
          for (int ni = 0; ni < 8; ni++)
            acc[mi][ni] = __builtin_amdgcn_mfma_f32_16x16x32_bf16(
                af[mi], bfr[ni], acc[mi][ni], 0, 0, 0);
      }
      __syncthreads();
    }

    if (strad)
      epilogue<true >(acc, sq, labels, i0, jwin, wm, wn, quad, lc, ibuf, jbuf);
    else
      epilogue<false>(acc, sq, labels, i0, jwin, wm, wn, quad, lc, ibuf, jbuf);
    __syncthreads();

    // in-block combine + plain stores to disjoint slots
    if (tid < 128) {
      unsigned p = max(ibuf[0][tid][0], ibuf[1][tid][0]);
      unsigned n = min(ibuf[0][tid][1], ibuf[1][tid][1]);
      pos_i[(size_t)Js * BATCH + i0 + tid] = p;
      neg_i[(size_t)Js * BATCH + i0 + tid] = n;
    }
    if (!strad) {
      unsigned p = max(jbuf[0][tid][0], jbuf[1][tid][0]);
      unsigned n = min(jbuf[0][tid][1], jbuf[1][tid][1]);
      pos_j[(size_t)It * BATCH + jwin + tid] = p;
      neg_j[(size_t)It * BATCH + jwin + tid] = n;
    }
    __syncthreads();   // protect ibuf/jbuf reads from next tile's epilogue writes
  }
}

// ---------------- final: combine slots (enc-uint domain = d^2), terms, global mean ---------
__global__ __launch_bounds__(256) void final_kernel(
    const unsigned* __restrict__ pos_i, const unsigned* __restrict__ neg_i,
    const unsigned* __restrict__ pos_j, const unsigned* __restrict__ neg_j,
    const float* __restrict__ sq, unsigned* __restrict__ ctrl,
    float* __restrict__ out) {
  int i = blockIdx.x * 256 + threadIdx.x;   // 32 blocks x 256 = 8192
  unsigned pe = 0u, ne = 0xFFFFFFFFu;       // sentinels lose every comparison
  #pragma unroll 4
  for (int s = 0; s < 32; s++) {
    pe = max(pe, pos_i[(size_t)s * BATCH + i]);
    ne = min(ne, neg_i[(size_t)s * BATCH + i]);
  }
  #pragma unroll 4
  for (int s = 0; s < 64; s++) {
    pe = max(pe, pos_j[(size_t)s * BATCH + i]);
    ne = min(ne, neg_j[(size_t)s * BATCH + i]);
  }
  float p = dec(pe), n = dec(ne);           // p,n are d^2 values directly (z-trick)
  float term = 0.f, cnt = 0.f;
  if (p > -1e37f && n < 1e37f) {            // sentinel decodes fail => invalid row
    float dp = sqrtf(fmaxf(p, 0.f) + 1e-16f);
    float dn = sqrtf(fmaxf(n, 0.f) + 1e-16f);
    term = fmaxf(dp - dn + 0.3f, 0.f);
    cnt = 1.f;
  }
  #pragma unroll
  for (int off = 32; off > 0; off >>= 1) {
    term += __shfl_down(term, off);
    cnt  += __shfl_down(cnt, off);
  }
  __shared__ float ss[4], sc[4];
  int wave = threadIdx.x >> 6, lane = threadIdx.x & 63;
  if (lane == 0) { ss[wave] = term; sc[wave] = cnt; }
  __syncthreads();
  if (threadIdx.x == 0) {
    atomicAdd((float*)&ctrl[0], ss[0] + ss[1] + ss[2] + ss[3]);
    atomicAdd((float*)&ctrl[1], sc[0] + sc[1] + sc[2] + sc[3]);
    __threadfence();
    unsigned t = atomicAdd(&ctrl[2], 1u);
    if (t == 31u) {
      float S = atomicAdd((float*)&ctrl[0], 0.f);
      float C = atomicAdd((float*)&ctrl[1], 0.f);
      out[0] = S / fmaxf(C, 1.f);
    }
  }
}

extern "C" void kernel_launch(void* const* d_in, const int* in_sizes, int n_in,
                              void* d_out, int out_size, void* d_ws, size_t ws_size,
                              hipStream_t stream) {
  const float* X      = (const float*)d_in[0];
  const int*   labels = (const int*)d_in[1];
  float* out = (float*)d_out;
  char* ws = (char*)d_ws;

  const size_t SLOT = (size_t)BATCH * 4;                 // 32 KB per slot
  unsigned short* Xb = (unsigned short*)ws;              // 8 MB
  float* sq      = (float*)(ws + (8u << 20));            // 32 KB
  unsigned* ctrl = (unsigned*)(ws + (8u << 20) + (32u << 10)); // sums|ticket|queue
  char*  posb = ws + (8u << 20) + (64u << 10);           // 96 slots = 3 MB
  char*  negb = posb + 96 * SLOT;                        // 96 slots = 3 MB
  unsigned* pos_i = (unsigned*)posb;                     // 32 slots keyed Js
  unsigned* pos_j = (unsigned*)(posb + 32 * SLOT);       // 64 slots keyed It
  unsigned* neg_i = (unsigned*)negb;
  unsigned* neg_j = (unsigned*)(negb + 32 * SLOT);

  prep_kernel<<<BATCH / 4, 256, 0, stream>>>(X, Xb, sq, ctrl,
                                             (uint4*)posb, (uint4*)negb);
  triplet_mfma<<<512, 256, 0, stream>>>(Xb, sq, labels, ctrl,
                                        pos_i, neg_i, pos_j, neg_j);
  final_kernel<<<BATCH / 256, 256, 0, stream>>>(pos_i, neg_i, pos_j, neg_j, sq, ctrl, out);
}

// Round 14
// 141.550 us; speedup vs baseline: 1.4981x; 1.4981x over previous
//
#include <hip/hip_runtime.h>

#define BATCH 8192
#define DIM   512
#define NTILE 1056          // 64 straddle + 992 above-diagonal 128x256 tiles

typedef __attribute__((ext_vector_type(4))) float  f32x4;
typedef __attribute__((ext_vector_type(8))) __bf16 bf16x8;

__device__ __forceinline__ unsigned short f2bf(float x) {
  unsigned u = __float_as_uint(x);
  u = (u + 0x7FFFu + ((u >> 16) & 1u)) >> 16;   // RNE
  return (unsigned short)u;
}

__device__ __forceinline__ void load_lds16(const void* g, void* l) {
  __builtin_amdgcn_global_load_lds(
      (__attribute__((address_space(1))) void*)(g),
      (__attribute__((address_space(3))) void*)(l), 16, 0, 0);
}

// monotone float <-> uint encoding (order-preserving)
__device__ __forceinline__ unsigned enc(float f) {
  unsigned u = __float_as_uint(f);
  return u ^ (unsigned)(((int)u >> 31) | 0x80000000);
}
__device__ __forceinline__ float dec(unsigned k) {
  unsigned u = (k & 0x80000000u) ? (k ^ 0x80000000u) : ~k;
  return __uint_as_float(u);
}

// ---------------- prep: fp32->bf16, row norms, ctrl zeroing (NO seeding: final reads
// only exactly-written slot ranges, bounds proven by R11's passing run) ----------------
__global__ __launch_bounds__(256) void prep_kernel(
    const float* __restrict__ X, unsigned short* __restrict__ Xb,
    float* __restrict__ sq, unsigned* __restrict__ ctrl) {
  if (blockIdx.x == 0 && threadIdx.x == 0) {
    ((float*)ctrl)[0] = 0.f;                   // sum of terms
    ((float*)ctrl)[1] = 0.f;                   // count
    ctrl[2] = 0u;                              // finish ticket
    ctrl[3] = 0u;                              // tile queue head
  }
  int wave = threadIdx.x >> 6, lane = threadIdx.x & 63;
  int row = blockIdx.x * 4 + wave;             // 2048 blocks * 4 waves = 8192 rows
  const float4* xr = (const float4*)(X + (size_t)row * DIM);
  float4 a = xr[lane * 2];
  float4 b = xr[lane * 2 + 1];
  float s = a.x*a.x + a.y*a.y + a.z*a.z + a.w*a.w
          + b.x*b.x + b.y*b.y + b.z*b.z + b.w*b.w;
  uint4 p;
  p.x = (unsigned)f2bf(a.x) | ((unsigned)f2bf(a.y) << 16);
  p.y = (unsigned)f2bf(a.z) | ((unsigned)f2bf(a.w) << 16);
  p.z = (unsigned)f2bf(b.x) | ((unsigned)f2bf(b.y) << 16);
  p.w = (unsigned)f2bf(b.z) | ((unsigned)f2bf(b.w) << 16);
  ((uint4*)(Xb + (size_t)row * DIM))[lane] = p;
  #pragma unroll
  for (int off = 32; off > 0; off >>= 1) s += __shfl_down(s, off);
  if (lane == 0) sq[row] = s;
}

// Epilogue for one 128x256 tile: R12-verbatim (z-trick reverted: its shared operands
// extended liveness past the 128 arch-VGPR budget left by the 128-AGPR acc -> spill).
template<bool STRAD>
__device__ __forceinline__ void epilogue(
    const f32x4 (&acc)[4][8], const float* __restrict__ sq,
    const int* __restrict__ labels,
    int i0, int jwin, int wm, int wn, int quad, int lc,
    unsigned (*ibuf)[128][2], unsigned (*jbuf)[256][2]) {
  float sqj_r[8]; int labj_r[8];
  #pragma unroll
  for (int ni = 0; ni < 8; ni++) {
    int j = jwin + wn * 128 + ni * 16 + lc;
    sqj_r[ni] = sq[j]; labj_r[ni] = labels[j];
  }
  float rpos[16], rneg[16];
  float jp[8], jn[8];
  #pragma unroll
  for (int x = 0; x < 8; x++) { jp[x] = -3e38f; jn[x] = 3e38f; }
  #pragma unroll
  for (int mi = 0; mi < 4; mi++) {
    #pragma unroll
    for (int r = 0; r < 4; r++) {
      int ig = i0 + wm * 64 + mi * 16 + quad * 4 + r;
      int li = labels[ig];
      float si = sq[ig];
      float rp = -3e38f, rn = 3e38f;
      #pragma unroll
      for (int ni = 0; ni < 8; ni++) {
        float a = acc[mi][ni][r];
        float v = fmaf(-2.f, a, sqj_r[ni]);        // sq_j - 2dot (sq_i added at end)
        bool same = (li == labj_r[ni]);
        bool posok = same;
        if (STRAD) posok = same && ((jwin + wn * 128 + ni * 16 + lc) != ig);
        rp = fmaxf(rp, posok ? v : -3e38f);
        rn = fminf(rn, same ? 3e38f : v);
        if (!STRAD) {                              // j-mining: sq_i - 2dot per column
          float v2 = fmaf(-2.f, a, si);
          jp[ni] = fmaxf(jp[ni], same ? v2 : -3e38f);
          jn[ni] = fminf(jn[ni], same ? 3e38f : v2);
        }
      }
      rpos[mi * 4 + r] = rp; rneg[mi * 4 + r] = rn;
    }
  }
  #pragma unroll
  for (int m = 1; m <= 8; m <<= 1)
    #pragma unroll
    for (int x = 0; x < 16; x++) {
      rpos[x] = fmaxf(rpos[x], __shfl_xor(rpos[x], m));
      rneg[x] = fminf(rneg[x], __shfl_xor(rneg[x], m));
    }
  if (lc == 0) {
    #pragma unroll
    for (int mi = 0; mi < 4; mi++)
      #pragma unroll
      for (int r = 0; r < 4; r++) {
        int row = wm * 64 + mi * 16 + quad * 4 + r;
        ibuf[wn][row][0] = enc(rpos[mi * 4 + r]);
        ibuf[wn][row][1] = enc(rneg[mi * 4 + r]);
      }
  }
  if (!STRAD) {
    #pragma unroll
    for (int m = 16; m <= 32; m <<= 1)
      #pragma unroll
      for (int x = 0; x < 8; x++) {
        jp[x] = fmaxf(jp[x], __shfl_xor(jp[x], m));
        jn[x] = fminf(jn[x], __shfl_xor(jn[x], m));
      }
    if (quad == 0) {
      #pragma unroll
      for (int ni = 0; ni < 8; ni++) {
        int col = wn * 128 + ni * 16 + lc;
        jbuf[wm][col][0] = enc(jp[ni]);
        jbuf[wm][col][1] = enc(jn[ni]);
      }
    }
  }
}

// ---------------- main: R12-verbatim (best measured: 66us main, 135.3us e2e) ----------------
__global__ __launch_bounds__(256, 2) void triplet_mfma(
    const unsigned short* __restrict__ Xb, const float* __restrict__ sq,
    const int* __restrict__ labels, unsigned* __restrict__ ctrl,
    unsigned* __restrict__ pos_i, unsigned* __restrict__ neg_i,
    unsigned* __restrict__ pos_j, unsigned* __restrict__ neg_j) {
  __shared__ __align__(16) unsigned short Asm[128 * 64];  // 16 KB
  __shared__ __align__(16) unsigned short Bsm[256 * 64];  // 32 KB
  __shared__ unsigned ibuf[2][128][2];                    // 2 KB
  __shared__ unsigned jbuf[2][256][2];                    // 4 KB
  __shared__ int tshare;

  int tid = threadIdx.x;
  int wave = tid >> 6, lane = tid & 63;
  int wm = wave >> 1, wn = wave & 1;
  int quad = lane >> 4, lc = lane & 15;
  int rc = lane >> 3;
  int gcol = ((lane & 7) ^ rc) * 8;          // XOR swizzle (verified: 0 conflicts)

  for (;;) {
    if (tid == 0) tshare = (int)atomicAdd(&ctrl[3], 1u);
    __syncthreads();
    int t = tshare;
    if (t >= NTILE) break;

    int It, Js; bool strad;
    if (t < 64) { It = t; Js = t >> 1; strad = true; }
    else {
      int u = t - 64; It = 0; Js = 0; strad = false;
      for (int s = 0; s < 64; s++) {
        int c = 31 - (s >> 1);
        if (u < c) { It = s; Js = (s >> 1) + 1 + u; break; }
        u -= c;
      }
    }
    int i0 = It * 128, jwin = Js * 256;

    f32x4 acc[4][8];
    #pragma unroll
    for (int mi = 0; mi < 4; mi++)
      #pragma unroll
      for (int ni = 0; ni < 8; ni++)
        acc[mi][ni] = (f32x4){0.f, 0.f, 0.f, 0.f};

    for (int k0 = 0; k0 < DIM; k0 += 64) {
      #pragma unroll
      for (int tt = 0; tt < 4; tt++) {
        int c = wave * 4 + tt;
        int row = c * 8 + rc;
        load_lds16(Xb + (size_t)(i0 + row) * DIM + k0 + gcol, &Asm[c * 512]);
      }
      #pragma unroll
      for (int tt = 0; tt < 8; tt++) {
        int c = wave * 8 + tt;
        int row = c * 8 + rc;
        load_lds16(Xb + (size_t)(jwin + row) * DIM + k0 + gcol, &Bsm[c * 512]);
      }
      __syncthreads();
      #pragma unroll
      for (int kk = 0; kk < 64; kk += 32) {
        int kc = kk >> 3;
        int asel = ((kc + quad) ^ (lc & 7)) * 8;
        bf16x8 af[4], bfr[8];
        #pragma unroll
        for (int mi = 0; mi < 4; mi++)
          af[mi] = *(const bf16x8*)&Asm[(wm * 64 + mi * 16 + lc) * 64 + asel];
        #pragma unroll
        for (int ni = 0; ni < 8; ni++)
          bfr[ni] = *(const bf16x8*)&Bsm[(wn * 128 + ni * 16 + lc) * 64 + asel];
        #pragma unroll
        for (int mi = 0; mi < 4; mi++)
          #pragma unroll
          for (int ni = 0; ni < 8; ni++)
            acc[mi][ni] = __builtin_amdgcn_mfma_f32_16x16x32_bf16(
                af[mi], bfr[ni], acc[mi][ni], 0, 0, 0);
      }
      __syncthreads();
    }

    if (strad)
      epilogue<true >(acc, sq, labels, i0, jwin, wm, wn, quad, lc, ibuf, jbuf);
    else
      epilogue<false>(acc, sq, labels, i0, jwin, wm, wn, quad, lc, ibuf, jbuf);
    __syncthreads();

    // in-block combine + plain stores to disjoint slots
    if (tid < 128) {
      unsigned p = max(ibuf[0][tid][0], ibuf[1][tid][0]);
      unsigned n = min(ibuf[0][tid][1], ibuf[1][tid][1]);
      pos_i[(size_t)Js * BATCH + i0 + tid] = p;
      neg_i[(size_t)Js * BATCH + i0 + tid] = n;
    }
    if (!strad) {
      unsigned p = max(jbuf[0][tid][0], jbuf[1][tid][0]);
      unsigned n = min(jbuf[0][tid][1], jbuf[1][tid][1]);
      pos_j[(size_t)It * BATCH + jwin + tid] = p;
      neg_j[(size_t)It * BATCH + jwin + tid] = n;
    }
    __syncthreads();   // protect ibuf/jbuf reads from next tile's epilogue writes
  }
}

// ---------------- final: combine ONLY exactly-written slot ranges, terms, global mean ------
// Row-block b = i>>7: i-slots Js in [b>>1, 32); j-slots It in [0, b&~1).
// Ranges proven correct by R11's passing run (same W(b) arithmetic). No sentinels needed.
// b is wave-uniform (64 consecutive rows sit inside one 128-row block) -> no divergence.
__global__ __launch_bounds__(256) void final_kernel(
    const unsigned* __restrict__ pos_i, const unsigned* __restrict__ neg_i,
    const unsigned* __restrict__ pos_j, const unsigned* __restrict__ neg_j,
    const float* __restrict__ sq, unsigned* __restrict__ ctrl,
    float* __restrict__ out) {
  int i = blockIdx.x * 256 + threadIdx.x;   // 32 blocks x 256 = 8192
  int b = i >> 7;
  unsigned pe = 0u, ne = 0xFFFFFFFFu;       // "loses every comparison" init
  for (int s = b >> 1; s < 32; s++) {
    pe = max(pe, pos_i[(size_t)s * BATCH + i]);
    ne = min(ne, neg_i[(size_t)s * BATCH + i]);
  }
  int jend = b & ~1;
  for (int s = 0; s < jend; s++) {
    pe = max(pe, pos_j[(size_t)s * BATCH + i]);
    ne = min(ne, neg_j[(size_t)s * BATCH + i]);
  }
  float p = dec(pe), n = dec(ne);
  float term = 0.f, cnt = 0.f;
  if (p > -1e37f && n < 1e37f) {            // -3e38/+3e38 mined sentinels => invalid row
    float si = sq[i];
    float dp = sqrtf(fmaxf(si + p, 0.f) + 1e-16f);
    float dn = sqrtf(fmaxf(si + n, 0.f) + 1e-16f);
    term = fmaxf(dp - dn + 0.3f, 0.f);
    cnt = 1.f;
  }
  #pragma unroll
  for (int off = 32; off > 0; off >>= 1) {
    term += __shfl_down(term, off);
    cnt  += __shfl_down(cnt, off);
  }
  __shared__ float ss[4], sc[4];
  int wave = threadIdx.x >> 6, lane = threadIdx.x & 63;
  if (lane == 0) { ss[wave] = term; sc[wave] = cnt; }
  __syncthreads();
  if (threadIdx.x == 0) {
    atomicAdd((float*)&ctrl[0], ss[0] + ss[1] + ss[2] + ss[3]);
    atomicAdd((float*)&ctrl[1], sc[0] + sc[1] + sc[2] + sc[3]);
    __threadfence();
    unsigned t = atomicAdd(&ctrl[2], 1u);
    if (t == 31u) {
      float S = atomicAdd((float*)&ctrl[0], 0.f);
      float C = atomicAdd((float*)&ctrl[1], 0.f);
      out[0] = S / fmaxf(C, 1.f);
    }
  }
}

extern "C" void kernel_launch(void* const* d_in, const int* in_sizes, int n_in,
                              void* d_out, int out_size, void* d_ws, size_t ws_size,
                              hipStream_t stream) {
  const float* X      = (const float*)d_in[0];
  const int*   labels = (const int*)d_in[1];
  float* out = (float*)d_out;
  char* ws = (char*)d_ws;

  const size_t SLOT = (size_t)BATCH * 4;                 // 32 KB per slot
  unsigned short* Xb = (unsigned short*)ws;              // 8 MB
  float* sq      = (float*)(ws + (8u << 20));            // 32 KB
  unsigned* ctrl = (unsigned*)(ws + (8u << 20) + (32u << 10)); // sums|ticket|queue
  char*  posb = ws + (8u << 20) + (64u << 10);           // 96 slots = 3 MB
  char*  negb = posb + 96 * SLOT;                        // 96 slots = 3 MB
  unsigned* pos_i = (unsigned*)posb;                     // 32 slots keyed Js
  unsigned* pos_j = (unsigned*)(posb + 32 * SLOT);       // 64 slots keyed It
  unsigned* neg_i = (unsigned*)negb;
  unsigned* neg_j = (unsigned*)(negb + 32 * SLOT);

  prep_kernel<<<BATCH / 4, 256, 0, stream>>>(X, Xb, sq, ctrl);
  triplet_mfma<<<512, 256, 0, stream>>>(Xb, sq, labels, ctrl,
                                        pos_i, neg_i, pos_j, neg_j);
  final_kernel<<<BATCH / 256, 256, 0, stream>>>(pos_i, neg_i, pos_j, neg_j, sq, ctrl, out);
}

// Round 15
// 135.041 us; speedup vs baseline: 1.5703x; 1.0482x over previous
//
#include <hip/hip_runtime.h>

#define BATCH 8192
#define DIM   512
#define NTILE 1056          // 64 straddle + 992 above-diagonal 128x256 tiles

typedef __attribute__((ext_vector_type(4))) float  f32x4;
typedef __attribute__((ext_vector_type(8))) __bf16 bf16x8;

__device__ __forceinline__ unsigned short f2bf(float x) {
  unsigned u = __float_as_uint(x);
  u = (u + 0x7FFFu + ((u >> 16) & 1u)) >> 16;   // RNE
  return (unsigned short)u;
}

__device__ __forceinline__ void load_lds16(const void* g, void* l) {
  __builtin_amdgcn_global_load_lds(
      (__attribute__((address_space(1))) void*)(g),
      (__attribute__((address_space(3))) void*)(l), 16, 0, 0);
}

// monotone float <-> uint encoding (order-preserving); sentinels 0x00000000 / 0xFFFFFFFF
__device__ __forceinline__ unsigned enc(float f) {
  unsigned u = __float_as_uint(f);
  return u ^ (unsigned)(((int)u >> 31) | 0x80000000);
}
__device__ __forceinline__ float dec(unsigned k) {
  unsigned u = (k & 0x80000000u) ? (k ^ 0x80000000u) : ~k;
  return __uint_as_float(u);
}

// ---------------- prep: fp32->bf16, row norms, sentinel seeding, ctrl zeroing --------------
// (single-thread ctrl writes in kernel N are visible to kernel N+1's atomics: proven R7-R14)
__global__ __launch_bounds__(256) void prep_kernel(
    const float* __restrict__ X, unsigned short* __restrict__ Xb,
    float* __restrict__ sq, unsigned* __restrict__ ctrl,
    uint4* __restrict__ pos4, uint4* __restrict__ neg4) {
  int gid = blockIdx.x * 256 + threadIdx.x;
  if (gid == 0) {
    ((float*)ctrl)[0] = 0.f;                   // sum of terms
    ((float*)ctrl)[1] = 0.f;                   // count
    ctrl[2] = 0u;                              // finish ticket
    ctrl[3] = 0u;                              // tile queue head
  }
  if (gid < 196608) {                          // 96 slots * 8192 * 4B / 16B
    pos4[gid] = (uint4){0u, 0u, 0u, 0u};       // enc-min sentinel (loses every max)
    neg4[gid] = (uint4){~0u, ~0u, ~0u, ~0u};   // enc-max sentinel (loses every min)
  }
  int wave = threadIdx.x >> 6, lane = threadIdx.x & 63;
  int row = blockIdx.x * 4 + wave;             // 2048 blocks * 4 waves = 8192 rows
  const float4* xr = (const float4*)(X + (size_t)row * DIM);
  float4 a = xr[lane * 2];
  float4 b = xr[lane * 2 + 1];
  float s = a.x*a.x + a.y*a.y + a.z*a.z + a.w*a.w
          + b.x*b.x + b.y*b.y + b.z*b.z + b.w*b.w;
  uint4 p;
  p.x = (unsigned)f2bf(a.x) | ((unsigned)f2bf(a.y) << 16);
  p.y = (unsigned)f2bf(a.z) | ((unsigned)f2bf(a.w) << 16);
  p.z = (unsigned)f2bf(b.x) | ((unsigned)f2bf(b.y) << 16);
  p.w = (unsigned)f2bf(b.z) | ((unsigned)f2bf(b.w) << 16);
  ((uint4*)(Xb + (size_t)row * DIM))[lane] = p;
  #pragma unroll
  for (int off = 32; off > 0; off >>= 1) s += __shfl_down(s, off);
  if (lane == 0) sq[row] = s;
}

// Epilogue for one 128x256 tile: i-mining always; j-mining (transposed) unless STRAD.
// (11 VALU/elem version — z-trick sharing spills: R13; keep liveness minimal.)
template<bool STRAD>
__device__ __forceinline__ void epilogue(
    const f32x4 (&acc)[4][8], const float* __restrict__ sq,
    const int* __restrict__ labels,
    int i0, int jwin, int wm, int wn, int quad, int lc,
    unsigned (*ibuf)[128][2], unsigned (*jbuf)[256][2]) {
  float sqj_r[8]; int labj_r[8];
  #pragma unroll
  for (int ni = 0; ni < 8; ni++) {
    int j = jwin + wn * 128 + ni * 16 + lc;
    sqj_r[ni] = sq[j]; labj_r[ni] = labels[j];
  }
  float rpos[16], rneg[16];
  float jp[8], jn[8];
  #pragma unroll
  for (int x = 0; x < 8; x++) { jp[x] = -3e38f; jn[x] = 3e38f; }
  #pragma unroll
  for (int mi = 0; mi < 4; mi++) {
    #pragma unroll
    for (int r = 0; r < 4; r++) {
      int ig = i0 + wm * 64 + mi * 16 + quad * 4 + r;
      int li = labels[ig];
      float si = sq[ig];
      float rp = -3e38f, rn = 3e38f;
      #pragma unroll
      for (int ni = 0; ni < 8; ni++) {
        float a = acc[mi][ni][r];
        float v = fmaf(-2.f, a, sqj_r[ni]);        // sq_j - 2dot (sq_i added at end)
        bool same = (li == labj_r[ni]);
        bool posok = same;
        if (STRAD) posok = same && ((jwin + wn * 128 + ni * 16 + lc) != ig);
        rp = fmaxf(rp, posok ? v : -3e38f);
        rn = fminf(rn, same ? 3e38f : v);
        if (!STRAD) {                              // j-mining: sq_i - 2dot per column
          float v2 = fmaf(-2.f, a, si);
          jp[ni] = fmaxf(jp[ni], same ? v2 : -3e38f);
          jn[ni] = fminf(jn[ni], same ? 3e38f : v2);
        }
      }
      rpos[mi * 4 + r] = rp; rneg[mi * 4 + r] = rn;
    }
  }
  #pragma unroll
  for (int m = 1; m <= 8; m <<= 1)
    #pragma unroll
    for (int x = 0; x < 16; x++) {
      rpos[x] = fmaxf(rpos[x], __shfl_xor(rpos[x], m));
      rneg[x] = fminf(rneg[x], __shfl_xor(rneg[x], m));
    }
  if (lc == 0) {
    #pragma unroll
    for (int mi = 0; mi < 4; mi++)
      #pragma unroll
      for (int r = 0; r < 4; r++) {
        int row = wm * 64 + mi * 16 + quad * 4 + r;
        ibuf[wn][row][0] = enc(rpos[mi * 4 + r]);
        ibuf[wn][row][1] = enc(rneg[mi * 4 + r]);
      }
  }
  if (!STRAD) {
    #pragma unroll
    for (int m = 16; m <= 32; m <<= 1)
      #pragma unroll
      for (int x = 0; x < 8; x++) {
        jp[x] = fmaxf(jp[x], __shfl_xor(jp[x], m));
        jn[x] = fminf(jn[x], __shfl_xor(jn[x], m));
      }
    if (quad == 0) {
      #pragma unroll
      for (int ni = 0; ni < 8; ni++) {
        int col = wn * 128 + ni * 16 + lc;
        jbuf[wm][col][0] = enc(jp[ni]);
        jbuf[wm][col][1] = enc(jn[ni]);
      }
    }
  }
}

// ---------------- main: R12-verbatim (session best: 66us main, 135.3us e2e) ----------------
// 1056 tiles of 128x256, dynamic atomic queue, 2 blocks/CU, XOR-swizzled LDS
// (0 conflicts), plain enc-uint stores to disjoint slots. NO fences, NO per-tile
// device sync (R3/R8/R11: any per-tile device-scope sync costs 2-4x).
__global__ __launch_bounds__(256, 2) void triplet_mfma(
    const unsigned short* __restrict__ Xb, const float* __restrict__ sq,
    const int* __restrict__ labels, unsigned* __restrict__ ctrl,
    unsigned* __restrict__ pos_i, unsigned* __restrict__ neg_i,
    unsigned* __restrict__ pos_j, unsigned* __restrict__ neg_j) {
  __shared__ __align__(16) unsigned short Asm[128 * 64];  // 16 KB
  __shared__ __align__(16) unsigned short Bsm[256 * 64];  // 32 KB
  __shared__ unsigned ibuf[2][128][2];                    // 2 KB
  __shared__ unsigned jbuf[2][256][2];                    // 4 KB
  __shared__ int tshare;

  int tid = threadIdx.x;
  int wave = tid >> 6, lane = tid & 63;
  int wm = wave >> 1, wn = wave & 1;
  int quad = lane >> 4, lc = lane & 15;
  int rc = lane >> 3;
  int gcol = ((lane & 7) ^ rc) * 8;          // XOR swizzle (verified: 0 conflicts)

  for (;;) {
    if (tid == 0) tshare = (int)atomicAdd(&ctrl[3], 1u);
    __syncthreads();
    int t = tshare;
    if (t >= NTILE) break;

    int It, Js; bool strad;
    if (t < 64) { It = t; Js = t >> 1; strad = true; }
    else {
      int u = t - 64; It = 0; Js = 0; strad = false;
      for (int s = 0; s < 64; s++) {
        int c = 31 - (s >> 1);
        if (u < c) { It = s; Js = (s >> 1) + 1 + u; break; }
        u -= c;
      }
    }
    int i0 = It * 128, jwin = Js * 256;

    f32x4 acc[4][8];
    #pragma unroll
    for (int mi = 0; mi < 4; mi++)
      #pragma unroll
      for (int ni = 0; ni < 8; ni++)
        acc[mi][ni] = (f32x4){0.f, 0.f, 0.f, 0.f};

    for (int k0 = 0; k0 < DIM; k0 += 64) {
      #pragma unroll
      for (int tt = 0; tt < 4; tt++) {
        int c = wave * 4 + tt;
        int row = c * 8 + rc;
        load_lds16(Xb + (size_t)(i0 + row) * DIM + k0 + gcol, &Asm[c * 512]);
      }
      #pragma unroll
      for (int tt = 0; tt < 8; tt++) {
        int c = wave * 8 + tt;
        int row = c * 8 + rc;
        load_lds16(Xb + (size_t)(jwin + row) * DIM + k0 + gcol, &Bsm[c * 512]);
      }
      __syncthreads();
      #pragma unroll
      for (int kk = 0; kk < 64; kk += 32) {
        int kc = kk >> 3;
        int asel = ((kc + quad) ^ (lc & 7)) * 8;
        bf16x8 af[4], bfr[8];
        #pragma unroll
        for (int mi = 0; mi < 4; mi++)
          af[mi] = *(const bf16x8*)&Asm[(wm * 64 + mi * 16 + lc) * 64 + asel];
        #pragma unroll
        for (int ni = 0; ni < 8; ni++)
          bfr[ni] = *(const bf16x8*)&Bsm[(wn * 128 + ni * 16 + lc) * 64 + asel];
        #pragma unroll
        for (int mi = 0; mi < 4; mi++)
          #pragma unroll
          for (int ni = 0; ni < 8; ni++)
            acc[mi][ni] = __builtin_amdgcn_mfma_f32_16x16x32_bf16(
                af[mi], bfr[ni], acc[mi][ni], 0, 0, 0);
      }
      __syncthreads();
    }

    if (strad)
      epilogue<true >(acc, sq, labels, i0, jwin, wm, wn, quad, lc, ibuf, jbuf);
    else
      epilogue<false>(acc, sq, labels, i0, jwin, wm, wn, quad, lc, ibuf, jbuf);
    __syncthreads();

    // in-block combine + plain stores to disjoint slots
    if (tid < 128) {
      unsigned p = max(ibuf[0][tid][0], ibuf[1][tid][0]);
      unsigned n = min(ibuf[0][tid][1], ibuf[1][tid][1]);
      pos_i[(size_t)Js * BATCH + i0 + tid] = p;
      neg_i[(size_t)Js * BATCH + i0 + tid] = n;
    }
    if (!strad) {
      unsigned p = max(jbuf[0][tid][0], jbuf[1][tid][0]);
      unsigned n = min(jbuf[0][tid][1], jbuf[1][tid][1]);
      pos_j[(size_t)It * BATCH + jwin + tid] = p;
      neg_j[(size_t)It * BATCH + jwin + tid] = n;
    }
    __syncthreads();   // protect ibuf/jbuf reads from next tile's epilogue writes
  }
}

// ---------------- final: combine slots (enc-uint domain), terms, global mean ----------------
__global__ __launch_bounds__(256) void final_kernel(
    const unsigned* __restrict__ pos_i, const unsigned* __restrict__ neg_i,
    const unsigned* __restrict__ pos_j, const unsigned* __restrict__ neg_j,
    const float* __restrict__ sq, unsigned* __restrict__ ctrl,
    float* __restrict__ out) {
  int i = blockIdx.x * 256 + threadIdx.x;   // 32 blocks x 256 = 8192
  unsigned pe = 0u, ne = 0xFFFFFFFFu;       // sentinels lose every comparison
  #pragma unroll 4
  for (int s = 0; s < 32; s++) {
    pe = max(pe, pos_i[(size_t)s * BATCH + i]);
    ne = min(ne, neg_i[(size_t)s * BATCH + i]);
  }
  #pragma unroll 4
  for (int s = 0; s < 64; s++) {
    pe = max(pe, pos_j[(size_t)s * BATCH + i]);
    ne = min(ne, neg_j[(size_t)s * BATCH + i]);
  }
  float p = dec(pe), n = dec(ne);
  float term = 0.f, cnt = 0.f;
  if (p > -1e37f && n < 1e37f) {            // sentinel decodes fail => invalid row
    float si = sq[i];
    float dp = sqrtf(fmaxf(si + p, 0.f) + 1e-16f);
    float dn = sqrtf(fmaxf(si + n, 0.f) + 1e-16f);
    term = fmaxf(dp - dn + 0.3f, 0.f);
    cnt = 1.f;
  }
  #pragma unroll
  for (int off = 32; off > 0; off >>= 1) {
    term += __shfl_down(term, off);
    cnt  += __shfl_down(cnt, off);
  }
  __shared__ float ss[4], sc[4];
  int wave = threadIdx.x >> 6, lane = threadIdx.x & 63;
  if (lane == 0) { ss[wave] = term; sc[wave] = cnt; }
  __syncthreads();
  if (threadIdx.x == 0) {
    atomicAdd((float*)&ctrl[0], ss[0] + ss[1] + ss[2] + ss[3]);
    atomicAdd((float*)&ctrl[1], sc[0] + sc[1] + sc[2] + sc[3]);
    __threadfence();
    unsigned t = atomicAdd(&ctrl[2], 1u);
    if (t == 31u) {
      float S = atomicAdd((float*)&ctrl[0], 0.f);
      float C = atomicAdd((float*)&ctrl[1], 0.f);
      out[0] = S / fmaxf(C, 1.f);
    }
  }
}

extern "C" void kernel_launch(void* const* d_in, const int* in_sizes, int n_in,
                              void* d_out, int out_size, void* d_ws, size_t ws_size,
                              hipStream_t stream) {
  const float* X      = (const float*)d_in[0];
  const int*   labels = (const int*)d_in[1];
  float* out = (float*)d_out;
  char* ws = (char*)d_ws;

  const size_t SLOT = (size_t)BATCH * 4;                 // 32 KB per slot
  unsigned short* Xb = (unsigned short*)ws;              // 8 MB
  float* sq      = (float*)(ws + (8u << 20));            // 32 KB
  unsigned* ctrl = (unsigned*)(ws + (8u << 20) + (32u << 10)); // sums|ticket|queue
  char*  posb = ws + (8u << 20) + (64u << 10);           // 96 slots = 3 MB
  char*  negb = posb + 96 * SLOT;                        // 96 slots = 3 MB
  unsigned* pos_i = (unsigned*)posb;                     // 32 slots keyed Js
  unsigned* pos_j = (unsigned*)(posb + 32 * SLOT);       // 64 slots keyed It
  unsigned* neg_i = (unsigned*)negb;
  unsigned* neg_j = (unsigned*)(negb + 32 * SLOT);

  prep_kernel<<<BATCH / 4, 256, 0, stream>>>(X, Xb, sq, ctrl,
                                             (uint4*)posb, (uint4*)negb);
  triplet_mfma<<<512, 256, 0, stream>>>(Xb, sq, labels, ctrl,
                                        pos_i, neg_i, pos_j, neg_j);
  final_kernel<<<BATCH / 256, 256, 0, stream>>>(pos_i, neg_i, pos_j, neg_j, sq, ctrl, out);
}